// Round 17
// baseline (44.485 us; speedup 1.0000x reference)
//
#include <hip/hip_runtime.h>
#include <hip/hip_fp16.h>

// Unsharp-mask: out = img + param * (img - gaussblur25(img)), param = 5*(tanh(f[b,0])*.5+.5)
// img: (16,3,512,512) fp32. Output: [out (12582912 fp32)] ++ [param (16 fp32)].
//
// R17 = R16 (stage f16 -> H -> tmpB -> packed-f16 V + LDS-center epilogue,
// XCD swizzle) with the H-pass moved to the idle MFMA pipe:
//   out16x16 = A(data rows x 40 taps) * B(Toeplitz GW), 2 chained
//   mfma_f32_16x16x32_f16 per tile (taps 0..31, 32..39). B is constant.
//   D layout (m89): row=(l>>4)*4+reg, col=l&15 -> 4 ds_write_b16/lane.
// Tile rows 88..95 of the last row-tile read garbage (tmpB region) -- MFMA
// rows are independent, those D rows land in tmpB rows 88..95, never read.

#define RADIUS 12
#define KS     25
#define TILE   64
#define PT     88                    // staged rows
#define TA_LD  104                   // tileA f16 stride (208B, 16B-aligned)
#define TB_LD  72                    // tmpB f16 stride (144B)
#define TB_ROWS 96                   // tmpB rows (88..95 = MFMA spill, unused)
#define IMG_W  512
#define IMG_H  512
#define PLANE  (IMG_W * IMG_H)
#define NPLANE 48

#define N_STAGE (PT * 11)            // 968 8px slots
#define LDS_HALVES (PT * TA_LD + TB_ROWS * TB_LD)   // 9152 + 6912 = 16064 (31.4 KB)

// Normalized 25-tap Gaussian, sigma=5
__device__ __constant__ float GW[KS] = {
    0.00453456f, 0.00718308f, 0.01093238f, 0.01598625f, 0.02245983f,
    0.03031760f, 0.03931982f, 0.04899550f, 0.05865827f, 0.06747307f,
    0.07456928f, 0.07918039f, 0.08077993f, 0.07918039f, 0.07456928f,
    0.06747307f, 0.05865827f, 0.04899550f, 0.03931982f, 0.03031760f,
    0.02245983f, 0.01598625f, 0.01093238f, 0.00718308f, 0.00453456f
};

__device__ __forceinline__ int reflect512(int i) {
    i = (i < 0) ? -i : i;
    return (i >= 512) ? (1022 - i) : i;
}

typedef _Float16 f16x8 __attribute__((ext_vector_type(8)));
typedef float f32x4 __attribute__((ext_vector_type(4)));

__device__ __forceinline__ unsigned h2u(__half2 h) {
    union { __half2 h; unsigned u; } x; x.h = h; return x.u;
}
__device__ __forceinline__ __half2 u2h(unsigned u) {
    union { unsigned u; __half2 h; } x; x.u = u; return x.h;
}
__device__ __forceinline__ float u_lo(unsigned u) {
    return __half2float(__low2half(u2h(u)));
}
__device__ __forceinline__ float u_hi(unsigned u) {
    return __half2float(__high2half(u2h(u)));
}

__global__ __launch_bounds__(256) void usm_fused_kernel(
    const float* __restrict__ img, const float* __restrict__ feat,
    float* __restrict__ out, float* __restrict__ out_param)
{
    __shared__ __align__(16) __half lds[LDS_HALVES];
#define TA(r, c) lds[(r) * TA_LD + (c)]
#define TB(r, c) lds[PT * TA_LD + (r) * TB_LD + (c)]

    // ---- bijective XCD swizzle: XCD k owns 6 contiguous z-planes ----
    const int bid  = blockIdx.x + 8 * blockIdx.y + 64 * blockIdx.z;   // 0..3071
    const int swz  = (bid & 7) * 384 + (bid >> 3);
    const int bx   = swz & 7;
    const int by   = (swz >> 3) & 7;
    const int zc   = swz >> 6;

    const int tid = threadIdx.x;
    const int tx0 = bx * TILE, ty0 = by * TILE;
    const int b   = zc / 3;
    const float param = (tanhf(feat[b * 8]) * 0.5f + 0.5f) * 5.0f;
    const float* __restrict__ src = img + (size_t)zc * PLANE;
    const bool xedge = (bx == 0) || (bx == 7);

    const int lane = tid & 63, wid = tid >> 6;
    const int r16 = lane & 15, kg = lane >> 4;

    // ---- constant Toeplitz B-fragments for the H MFMA ----
    // B1[k][c] = GW[k-c]   (k=kg*8+i, c=r16, valid 0<=k-c<25)
    // B2[k][c] = GW[32+k-c] (valid 32+k-c<25)
    f16x8 B1, B2;
#pragma unroll
    for (int i = 0; i < 8; ++i) {
        const int k = kg * 8 + i;
        const int d1 = k - r16;
        B1[i] = (d1 >= 0 && d1 < KS) ? (_Float16)GW[d1] : (_Float16)0.f;
        const int d2 = 32 + k - r16;
        B2[i] = (d2 < KS) ? (_Float16)GW[d2] : (_Float16)0.f;
    }

    // broadcast weight pairs for packed-f16 V
    __half2 GWh2[KS];
#pragma unroll
    for (int k = 0; k < KS; ++k)
        GWh2[k] = __floats2half2_rn(GW[k], GW[k]);

    // ---- Stage 88x88 padded tile as f16: 968 slots ----
#pragma unroll
    for (int it = 0; it < 4; ++it) {
        const int li = tid + it * 256;
        if (it < 3 || li < N_STAGE) {
            const int py = li / 11, s = li - py * 11;
            const int gy = reflect512(ty0 - RADIUS + py);
            const float* __restrict__ rowp = src + (size_t)gy * IMG_W;
            const int gx = tx0 - RADIUS + s * 8;
            float4 va, vb;
            if (!xedge) {
                va = *(const float4*)(rowp + gx);
                vb = *(const float4*)(rowp + gx + 4);
            } else {
                va.x = rowp[reflect512(gx)];     va.y = rowp[reflect512(gx + 1)];
                va.z = rowp[reflect512(gx + 2)]; va.w = rowp[reflect512(gx + 3)];
                vb.x = rowp[reflect512(gx + 4)]; vb.y = rowp[reflect512(gx + 5)];
                vb.z = rowp[reflect512(gx + 6)]; vb.w = rowp[reflect512(gx + 7)];
            }
            uint4 pk;
            pk.x = h2u(__floats2half2_rn(va.x, va.y));
            pk.y = h2u(__floats2half2_rn(va.z, va.w));
            pk.z = h2u(__floats2half2_rn(vb.x, vb.y));
            pk.w = h2u(__floats2half2_rn(vb.z, vb.w));
            *(uint4*)&TA(py, s * 8) = pk;
        }
    }
    __syncthreads();

    // ---- Horizontal via MFMA: 6 row-tiles x 4 col-tiles, 2 MFMA each ----
    // Wave w handles tiles w, w+4, ... (6 tiles/wave).
#pragma unroll
    for (int t = wid; t < 24; t += 4) {
        const int py0 = (t >> 2) * 16;      // 0,16,32,48,64,80
        const int c0  = (t & 3) * 16;       // 0,16,32,48  (tap base = output base)
        const f16x8 A1 = *(const f16x8*)&TA(py0 + r16, c0 + kg * 8);   // taps c0..c0+31
        const f16x8 A2 = *(const f16x8*)&TA(py0 + r16, c0 + 32);       // taps c0+32..39 (bcast)
        f32x4 d = {0.f, 0.f, 0.f, 0.f};
        d = __builtin_amdgcn_mfma_f32_16x16x32_f16(A2, B2, d, 0, 0, 0);
        d = __builtin_amdgcn_mfma_f32_16x16x32_f16(A1, B1, d, 0, 0, 0);
#pragma unroll
        for (int reg = 0; reg < 4; ++reg)
            TB(py0 + kg * 4 + reg, c0 + r16) = __float2half(d[reg]);
    }
    __syncthreads();

    // ---- Vertical (packed f16) + epilogue: 4x4 micro-tile per thread ----
    const int tx4 = (tid & 15) * 4, ry0 = (tid >> 4) * 4;

    __half2 aP0[4], aP1[4];
#pragma unroll
    for (int d = 0; d < 4; ++d) { aP0[d] = __half2(0, 0); aP1[d] = __half2(0, 0); }

#pragma unroll
    for (int k = 0; k < KS + 3; ++k) {         // 28 b64 row reads
        const uint2 rd = *(const uint2*)&TB(ry0 + k, tx4);
        const __half2 p0 = u2h(rd.x), p1 = u2h(rd.y);
#pragma unroll
        for (int d = 0; d < 4; ++d) {
            const int kk = k - d;
            if (kk >= 0 && kk < KS) {
                aP0[d] = __hfma2(GWh2[kk], p0, aP0[d]);
                aP1[d] = __hfma2(GWh2[kk], p1, aP1[d]);
            }
        }
    }

    float* __restrict__ dst = out + (size_t)zc * PLANE;
#pragma unroll
    for (int d = 0; d < 4; ++d) {
        const int oy = ty0 + ry0 + d;
        const uint2 cv = *(const uint2*)&TA(ry0 + d + RADIUS, tx4 + RADIUS);
        const float v0 = u_lo(cv.x), v1 = u_hi(cv.x), v2 = u_lo(cv.y), v3 = u_hi(cv.y);
        const float b0 = __half2float(__low2half(aP0[d])), b1 = __half2float(__high2half(aP0[d]));
        const float b2 = __half2float(__low2half(aP1[d])), b3 = __half2float(__high2half(aP1[d]));
        float4 o;
        o.x = v0 + param * (v0 - b0);
        o.y = v1 + param * (v1 - b1);
        o.z = v2 + param * (v2 - b2);
        o.w = v3 + param * (v3 - b3);
        *(float4*)(dst + (size_t)oy * IMG_W + tx0 + tx4) = o;
    }

    if (tid == 0 && bx == 0 && by == 0 && (zc - b * 3) == 0)
        out_param[b] = param;
#undef TA
#undef TB
}

extern "C" void kernel_launch(void* const* d_in, const int* in_sizes, int n_in,
                              void* d_out, int out_size, void* d_ws, size_t ws_size,
                              hipStream_t stream) {
    const float* img  = (const float*)d_in[0];
    const float* feat = (const float*)d_in[1];
    float* out       = (float*)d_out;
    float* out_param = (float*)d_out + (size_t)NPLANE * PLANE;

    usm_fused_kernel<<<dim3(8, 8, NPLANE), 256, 0, stream>>>(img, feat, out, out_param);
}

// Round 18
// 44.186 us; speedup vs baseline: 1.0068x; 1.0068x over previous
//
#include <hip/hip_runtime.h>
#include <hip/hip_fp16.h>

// Unsharp-mask: out = img + param * (img - gaussblur25(img)), param = 5*(tanh(f[b,0])*.5+.5)
// img: (16,3,512,512) fp32. Output: [out (12582912 fp32)] ++ [param (16 fp32)].
//
// R18 = R16 skeleton with H on the MFMA pipe, TRANSPOSED product:
//   D' = W_toeplitz (A-op) x data (B-op), so lane holds 4 consecutive
//   OUTPUT-X of one data row -> 2x cvt_pkrtz + ONE ds_write_b64 into
//   row-major tmpB (R17's 4 scalar b16 scatter writes were its regression).
// All fragment-layout assumptions silicon-verified by R17 (passed, correct).
// Stage f16, packed-f16 V, LDS-center epilogue, XCD swizzle: as R16.

#define RADIUS 12
#define KS     25
#define TILE   64
#define PT     88                    // staged rows
#define TA_LD  104                   // tileA f16 stride (208B)
#define TB_LD  72                    // tmpB f16 stride (144B)
#define TB_ROWS 96                   // rows 88..95 = MFMA spill (garbage cols), unused
#define IMG_W  512
#define IMG_H  512
#define PLANE  (IMG_W * IMG_H)
#define NPLANE 48

#define N_STAGE (PT * 11)            // 968 8px slots
#define LDS_HALVES (PT * TA_LD + TB_ROWS * TB_LD)   // 31.4 KB

// Normalized 25-tap Gaussian, sigma=5
__device__ __constant__ float GW[KS] = {
    0.00453456f, 0.00718308f, 0.01093238f, 0.01598625f, 0.02245983f,
    0.03031760f, 0.03931982f, 0.04899550f, 0.05865827f, 0.06747307f,
    0.07456928f, 0.07918039f, 0.08077993f, 0.07918039f, 0.07456928f,
    0.06747307f, 0.05865827f, 0.04899550f, 0.03931982f, 0.03031760f,
    0.02245983f, 0.01598625f, 0.01093238f, 0.00718308f, 0.00453456f
};

__device__ __forceinline__ int reflect512(int i) {
    i = (i < 0) ? -i : i;
    return (i >= 512) ? (1022 - i) : i;
}

typedef _Float16 f16x8 __attribute__((ext_vector_type(8)));
typedef float f32x4 __attribute__((ext_vector_type(4)));

__device__ __forceinline__ unsigned h2u(__half2 h) {
    union { __half2 h; unsigned u; } x; x.h = h; return x.u;
}
__device__ __forceinline__ __half2 u2h(unsigned u) {
    union { unsigned u; __half2 h; } x; x.u = u; return x.h;
}
__device__ __forceinline__ float u_lo(unsigned u) {
    return __half2float(__low2half(u2h(u)));
}
__device__ __forceinline__ float u_hi(unsigned u) {
    return __half2float(__high2half(u2h(u)));
}

__global__ __launch_bounds__(256) void usm_fused_kernel(
    const float* __restrict__ img, const float* __restrict__ feat,
    float* __restrict__ out, float* __restrict__ out_param)
{
    __shared__ __align__(16) __half lds[LDS_HALVES];
#define TA(r, c) lds[(r) * TA_LD + (c)]
#define TB(r, c) lds[PT * TA_LD + (r) * TB_LD + (c)]

    // ---- bijective XCD swizzle: XCD k owns 6 contiguous z-planes ----
    const int bid  = blockIdx.x + 8 * blockIdx.y + 64 * blockIdx.z;   // 0..3071
    const int swz  = (bid & 7) * 384 + (bid >> 3);
    const int bx   = swz & 7;
    const int by   = (swz >> 3) & 7;
    const int zc   = swz >> 6;

    const int tid = threadIdx.x;
    const int tx0 = bx * TILE, ty0 = by * TILE;
    const int b   = zc / 3;
    const float param = (tanhf(feat[b * 8]) * 0.5f + 0.5f) * 5.0f;
    const float* __restrict__ src = img + (size_t)zc * PLANE;
    const bool xedge = (bx == 0) || (bx == 7);

    const int lane = tid & 63, wid = tid >> 6;
    const int r16 = lane & 15, kg = lane >> 4;

    // ---- constant Toeplitz fragments (A-operand): X[m][k] = GW[k-m] ----
    // lane supplies X[m=r16][k=kg*8+i]; X2[m][k] = GW[32+k-m] (zero for kg>=1)
    f16x8 X1, X2;
#pragma unroll
    for (int i = 0; i < 8; ++i) {
        const int k = kg * 8 + i;
        const int d1 = k - r16;
        X1[i] = (d1 >= 0 && d1 < KS) ? (_Float16)GW[d1] : (_Float16)0.f;
        const int d2 = 32 + k - r16;
        X2[i] = (d2 < KS) ? (_Float16)GW[d2] : (_Float16)0.f;
    }

    // broadcast weight pairs for packed-f16 V
    __half2 GWh2[KS];
#pragma unroll
    for (int k = 0; k < KS; ++k)
        GWh2[k] = __floats2half2_rn(GW[k], GW[k]);

    // ---- Stage 88x88 padded tile as f16: 968 slots ----
#pragma unroll
    for (int it = 0; it < 4; ++it) {
        const int li = tid + it * 256;
        if (it < 3 || li < N_STAGE) {
            const int py = li / 11, s = li - py * 11;
            const int gy = reflect512(ty0 - RADIUS + py);
            const float* __restrict__ rowp = src + (size_t)gy * IMG_W;
            const int gx = tx0 - RADIUS + s * 8;
            float4 va, vb;
            if (!xedge) {
                va = *(const float4*)(rowp + gx);
                vb = *(const float4*)(rowp + gx + 4);
            } else {
                va.x = rowp[reflect512(gx)];     va.y = rowp[reflect512(gx + 1)];
                va.z = rowp[reflect512(gx + 2)]; va.w = rowp[reflect512(gx + 3)];
                vb.x = rowp[reflect512(gx + 4)]; vb.y = rowp[reflect512(gx + 5)];
                vb.z = rowp[reflect512(gx + 6)]; vb.w = rowp[reflect512(gx + 7)];
            }
            uint4 pk;
            pk.x = h2u(__floats2half2_rn(va.x, va.y));
            pk.y = h2u(__floats2half2_rn(va.z, va.w));
            pk.z = h2u(__floats2half2_rn(vb.x, vb.y));
            pk.w = h2u(__floats2half2_rn(vb.z, vb.w));
            *(uint4*)&TA(py, s * 8) = pk;
        }
    }
    __syncthreads();

    // ---- Horizontal via transposed MFMA: 6 row-tiles x 4 col-tiles ----
    // D'[m][n] = sum_k GW[k-m] * data[py0+n][c0+k] = Hblur[x=c0+m][row=py0+n].
    // Lane (kg,r16): D' rows m=4kg..4kg+3 at col n=r16 -> 4 consecutive
    // output-x at data row py0+r16 -> one b64 write to TB(py0+r16, c0+4kg).
#pragma unroll
    for (int t = wid; t < 24; t += 4) {
        const int py0 = (t >> 2) * 16;      // 0,16,32,48,64,80
        const int c0  = (t & 3) * 16;       // 0,16,32,48
        const f16x8 Y1 = *(const f16x8*)&TA(py0 + r16, c0 + kg * 8);   // data taps c0..c0+31
        const f16x8 Y2 = *(const f16x8*)&TA(py0 + r16, c0 + 32);       // taps c0+32..39 (kg=0 only)
        f32x4 d = {0.f, 0.f, 0.f, 0.f};
        d = __builtin_amdgcn_mfma_f32_16x16x32_f16(X2, Y2, d, 0, 0, 0);
        d = __builtin_amdgcn_mfma_f32_16x16x32_f16(X1, Y1, d, 0, 0, 0);
        uint2 w;
        w.x = h2u(__floats2half2_rn(d[0], d[1]));
        w.y = h2u(__floats2half2_rn(d[2], d[3]));
        *(uint2*)&TB(py0 + r16, c0 + kg * 4) = w;
    }
    __syncthreads();

    // ---- Vertical (packed f16) + epilogue: 4x4 micro-tile per thread ----
    const int tx4 = (tid & 15) * 4, ry0 = (tid >> 4) * 4;

    __half2 aP0[4], aP1[4];
#pragma unroll
    for (int d = 0; d < 4; ++d) { aP0[d] = __half2(0, 0); aP1[d] = __half2(0, 0); }

#pragma unroll
    for (int k = 0; k < KS + 3; ++k) {         // 28 b64 row reads
        const uint2 rd = *(const uint2*)&TB(ry0 + k, tx4);
        const __half2 p0 = u2h(rd.x), p1 = u2h(rd.y);
#pragma unroll
        for (int d = 0; d < 4; ++d) {
            const int kk = k - d;
            if (kk >= 0 && kk < KS) {
                aP0[d] = __hfma2(GWh2[kk], p0, aP0[d]);
                aP1[d] = __hfma2(GWh2[kk], p1, aP1[d]);
            }
        }
    }

    float* __restrict__ dst = out + (size_t)zc * PLANE;
#pragma unroll
    for (int d = 0; d < 4; ++d) {
        const int oy = ty0 + ry0 + d;
        const uint2 cv = *(const uint2*)&TA(ry0 + d + RADIUS, tx4 + RADIUS);
        const float v0 = u_lo(cv.x), v1 = u_hi(cv.x), v2 = u_lo(cv.y), v3 = u_hi(cv.y);
        const float b0 = __half2float(__low2half(aP0[d])), b1 = __half2float(__high2half(aP0[d]));
        const float b2 = __half2float(__low2half(aP1[d])), b3 = __half2float(__high2half(aP1[d]));
        float4 o;
        o.x = v0 + param * (v0 - b0);
        o.y = v1 + param * (v1 - b1);
        o.z = v2 + param * (v2 - b2);
        o.w = v3 + param * (v3 - b3);
        *(float4*)(dst + (size_t)oy * IMG_W + tx0 + tx4) = o;
    }

    if (tid == 0 && bx == 0 && by == 0 && (zc - b * 3) == 0)
        out_param[b] = param;
#undef TA
#undef TB
}

extern "C" void kernel_launch(void* const* d_in, const int* in_sizes, int n_in,
                              void* d_out, int out_size, void* d_ws, size_t ws_size,
                              hipStream_t stream) {
    const float* img  = (const float*)d_in[0];
    const float* feat = (const float*)d_in[1];
    float* out       = (float*)d_out;
    float* out_param = (float*)d_out + (size_t)NPLANE * PLANE;

    usm_fused_kernel<<<dim3(8, 8, NPLANE), 256, 0, stream>>>(img, feat, out, out_param);
}

// Round 19
// 34.795 us; speedup vs baseline: 1.2785x; 1.2699x over previous
//
#include <hip/hip_runtime.h>
#include <hip/hip_fp16.h>

// Unsharp-mask: out = img + param * (img - gaussblur25(img)), param = 5*(tanh(f[b,0])*.5+.5)
// img: (16,3,512,512) fp32. Output: [out (12582912 fp32)] ++ [param (16 fp32)].
//
// R19 = R16 (champion, 40.4us: stage f16 -> dot2 H -> tmpB -> packed-f16 V +
// LDS-center epilogue + XCD swizzle) with:
//  1) T14-lite prologue: stage LOADS issued first; weight tables + tanhf
//     computed while loads fly; cvt+LDS-write after.
//  2) per-SLOT edge handling: only slots with taps outside [0,511] take the
//     scalar reflect path (2 of 11 slots in edge blocks, 0 elsewhere).

#define RADIUS 12
#define KS     25
#define TILE   64
#define PT     88
#define TA_LD  104                   // tileA f16 stride (208B)
#define TB_LD  72                    // tmpB  f16 stride (144B)
#define IMG_W  512
#define IMG_H  512
#define PLANE  (IMG_W * IMG_H)
#define NPLANE 48

#define N_STAGE (PT * 11)            // 968 8px slots

// Normalized 25-tap Gaussian, sigma=5
__device__ __constant__ float GW[KS] = {
    0.00453456f, 0.00718308f, 0.01093238f, 0.01598625f, 0.02245983f,
    0.03031760f, 0.03931982f, 0.04899550f, 0.05865827f, 0.06747307f,
    0.07456928f, 0.07918039f, 0.08077993f, 0.07918039f, 0.07456928f,
    0.06747307f, 0.05865827f, 0.04899550f, 0.03931982f, 0.03031760f,
    0.02245983f, 0.01598625f, 0.01093238f, 0.00718308f, 0.00453456f
};

__device__ __forceinline__ int reflect512(int i) {
    i = (i < 0) ? -i : i;
    return (i >= 512) ? (1022 - i) : i;
}

typedef _Float16 h2_t __attribute__((ext_vector_type(2)));

__device__ __forceinline__ unsigned h2u(__half2 h) {
    union { __half2 h; unsigned u; } x; x.h = h; return x.u;
}
__device__ __forceinline__ __half2 u2h(unsigned u) {
    union { unsigned u; __half2 h; } x; x.u = u; return x.h;
}
__device__ __forceinline__ float u_lo(unsigned u) {
    return __half2float(__low2half(u2h(u)));
}
__device__ __forceinline__ float u_hi(unsigned u) {
    return __half2float(__high2half(u2h(u)));
}

#if __has_builtin(__builtin_amdgcn_fdot2)
__device__ __forceinline__ float fdot2u(unsigned a, unsigned b, float c) {
    union { unsigned u; h2_t h; } ua, ub;
    ua.u = a; ub.u = b;
    return __builtin_amdgcn_fdot2(ua.h, ub.h, c, false);
}
#else
__device__ __forceinline__ float fdot2u(unsigned a, unsigned b, float c) {
    return c + u_lo(a) * u_lo(b) + u_hi(a) * u_hi(b);
}
#endif

__global__ __launch_bounds__(256) void usm_fused_kernel(
    const float* __restrict__ img, const float* __restrict__ feat,
    float* __restrict__ out, float* __restrict__ out_param)
{
    __shared__ __half tileA[PT][TA_LD];   // 88x104 f16 = 17.9 KB
    __shared__ __half tmpB[PT][TB_LD];    // 88x72  f16 = 12.4 KB

    // ---- bijective XCD swizzle: XCD k owns 6 contiguous z-planes ----
    const int bid  = blockIdx.x + 8 * blockIdx.y + 64 * blockIdx.z;   // 0..3071
    const int swz  = (bid & 7) * 384 + (bid >> 3);
    const int bx   = swz & 7;
    const int by   = (swz >> 3) & 7;
    const int zc   = swz >> 6;

    const int tid = threadIdx.x;
    const int tx0 = bx * TILE, ty0 = by * TILE;
    const int b   = zc / 3;
    const float* __restrict__ src = img + (size_t)zc * PLANE;

    // ================= Stage: ISSUE LOADS FIRST (T14-lite) =================
    float4 sva[4], svb[4];
#pragma unroll
    for (int it = 0; it < 4; ++it) {
        const int li = tid + it * 256;
        if (it < 3 || li < N_STAGE) {
            const int py = li / 11, s = li - py * 11;
            const int gy = reflect512(ty0 - RADIUS + py);
            const float* __restrict__ rowp = src + (size_t)gy * IMG_W;
            const int gx = tx0 - RADIUS + s * 8;
            if (gx >= 0 && gx + 7 <= 511) {           // per-slot fast path
                sva[it] = *(const float4*)(rowp + gx);
                svb[it] = *(const float4*)(rowp + gx + 4);
            } else {                                   // reflect (2/11 slots, edge blocks only)
                float4 va, vb;
                va.x = rowp[reflect512(gx)];     va.y = rowp[reflect512(gx + 1)];
                va.z = rowp[reflect512(gx + 2)]; va.w = rowp[reflect512(gx + 3)];
                vb.x = rowp[reflect512(gx + 4)]; vb.y = rowp[reflect512(gx + 5)];
                vb.z = rowp[reflect512(gx + 6)]; vb.w = rowp[reflect512(gx + 7)];
                sva[it] = va; svb[it] = vb;
            }
        }
    }

    // ---- weight tables + param: computed while stage loads are in flight ----
    unsigned W2[12];
#pragma unroll
    for (int m = 0; m < 12; ++m)
        W2[m] = h2u(__floats2half2_rn(GW[2 * m], GW[2 * m + 1]));
    const unsigned WE = h2u(__floats2half2_rn(GW[24], 0.f));
    const unsigned WO = h2u(__floats2half2_rn(0.f, GW[24]));

    __half2 GWh2[KS];
#pragma unroll
    for (int k = 0; k < KS; ++k)
        GWh2[k] = __floats2half2_rn(GW[k], GW[k]);

    const float param = (tanhf(feat[b * 8]) * 0.5f + 0.5f) * 5.0f;

    // ---- stage write: pack f16 -> LDS ----
#pragma unroll
    for (int it = 0; it < 4; ++it) {
        const int li = tid + it * 256;
        if (it < 3 || li < N_STAGE) {
            const int py = li / 11, s = li - py * 11;
            uint4 pk;
            pk.x = h2u(__floats2half2_rn(sva[it].x, sva[it].y));
            pk.y = h2u(__floats2half2_rn(sva[it].z, sva[it].w));
            pk.z = h2u(__floats2half2_rn(svb[it].x, svb[it].y));
            pk.w = h2u(__floats2half2_rn(svb[it].z, svb[it].w));
            *(uint4*)&tileA[py][s * 8] = pk;
        }
    }
    __syncthreads();

    // ================= Horizontal via dot2: 704 slots =================
#pragma unroll
    for (int it = 0; it < 3; ++it) {
        const int li = tid + it * 256;
        if (it < 2 || li < PT * (TILE / 8)) {
            const int py = li >> 3, g = li & 7;
            const uint4 qa = *(const uint4*)&tileA[py][g * 8];
            const uint4 qb = *(const uint4*)&tileA[py][g * 8 + 8];
            const uint4 qc = *(const uint4*)&tileA[py][g * 8 + 16];
            const uint4 qd = *(const uint4*)&tileA[py][g * 8 + 24];

            unsigned P[16] = { qa.x, qa.y, qa.z, qa.w, qb.x, qb.y, qb.z, qb.w,
                               qc.x, qc.y, qc.z, qc.w, qd.x, qd.y, qd.z, qd.w };
            unsigned S[15];
#pragma unroll
            for (int i = 0; i < 15; ++i)
                S[i] = __builtin_amdgcn_alignbit(P[i + 1], P[i], 16);

            float acc[8];
#pragma unroll
            for (int h = 0; h < 4; ++h) {               // even outputs
                float a = 0.f;
#pragma unroll
                for (int m = 0; m < 12; ++m) a = fdot2u(P[h + m], W2[m], a);
                acc[2 * h] = fdot2u(P[h + 12], WE, a);
            }
#pragma unroll
            for (int h = 0; h < 4; ++h) {               // odd outputs
                float a = 0.f;
#pragma unroll
                for (int m = 0; m < 12; ++m) a = fdot2u(S[h + m], W2[m], a);
                acc[2 * h + 1] = fdot2u(P[h + 12], WO, a);
            }

            uint4 pk;
            pk.x = h2u(__floats2half2_rn(acc[0], acc[1]));
            pk.y = h2u(__floats2half2_rn(acc[2], acc[3]));
            pk.z = h2u(__floats2half2_rn(acc[4], acc[5]));
            pk.w = h2u(__floats2half2_rn(acc[6], acc[7]));
            *(uint4*)&tmpB[py][g * 8] = pk;
        }
    }
    __syncthreads();

    // ========== Vertical (packed f16) + epilogue: 4x4 micro-tile ==========
    const int tx4 = (tid & 15) * 4, ry0 = (tid >> 4) * 4;

    __half2 aP0[4], aP1[4];
#pragma unroll
    for (int d = 0; d < 4; ++d) { aP0[d] = __half2(0, 0); aP1[d] = __half2(0, 0); }

#pragma unroll
    for (int k = 0; k < KS + 3; ++k) {         // 28 b64 row reads
        const uint2 rd = *(const uint2*)&tmpB[ry0 + k][tx4];
        const __half2 p0 = u2h(rd.x), p1 = u2h(rd.y);
#pragma unroll
        for (int d = 0; d < 4; ++d) {
            const int kk = k - d;
            if (kk >= 0 && kk < KS) {
                aP0[d] = __hfma2(GWh2[kk], p0, aP0[d]);
                aP1[d] = __hfma2(GWh2[kk], p1, aP1[d]);
            }
        }
    }

    float* __restrict__ dst = out + (size_t)zc * PLANE;
#pragma unroll
    for (int d = 0; d < 4; ++d) {
        const int oy = ty0 + ry0 + d;
        const uint2 cv = *(const uint2*)&tileA[ry0 + d + RADIUS][tx4 + RADIUS];
        const float v0 = u_lo(cv.x), v1 = u_hi(cv.x), v2 = u_lo(cv.y), v3 = u_hi(cv.y);
        const float b0 = __half2float(__low2half(aP0[d])), b1 = __half2float(__high2half(aP0[d]));
        const float b2 = __half2float(__low2half(aP1[d])), b3 = __half2float(__high2half(aP1[d]));
        float4 o;
        o.x = v0 + param * (v0 - b0);
        o.y = v1 + param * (v1 - b1);
        o.z = v2 + param * (v2 - b2);
        o.w = v3 + param * (v3 - b3);
        *(float4*)(dst + (size_t)oy * IMG_W + tx0 + tx4) = o;
    }

    if (tid == 0 && bx == 0 && by == 0 && (zc - b * 3) == 0)
        out_param[b] = param;
}

extern "C" void kernel_launch(void* const* d_in, const int* in_sizes, int n_in,
                              void* d_out, int out_size, void* d_ws, size_t ws_size,
                              hipStream_t stream) {
    const float* img  = (const float*)d_in[0];
    const float* feat = (const float*)d_in[1];
    float* out       = (float*)d_out;
    float* out_param = (float*)d_out + (size_t)NPLANE * PLANE;

    usm_fused_kernel<<<dim3(8, 8, NPLANE), 256, 0, stream>>>(img, feat, out, out_param);
}